// Round 6
// baseline (30545.880 us; speedup 1.0000x reference)
//
#include <hip/hip_runtime.h>
#include <cstddef>

#define BB 32
#define TT 4096
#define PP 512
#define WW 1024

using u32 = unsigned;
using u64 = unsigned long long;

typedef short short8 __attribute__((ext_vector_type(8)));
typedef float f32x4 __attribute__((ext_vector_type(4)));

__device__ __forceinline__ u32 bfround(float f) {
    u32 u = __float_as_uint(f);
    return (u + 0x7fffu + ((u >> 16) & 1u)) >> 16;
}
__device__ __forceinline__ float bf2f(u32 q) { return __uint_as_float(q << 16); }
__device__ __forceinline__ float bflo(u32 q) { return __uint_as_float(q << 16); }
__device__ __forceinline__ float bfhi(u32 q) { return __uint_as_float(q & 0xffff0000u); }

#define LDA64(p)    __hip_atomic_load((p),  __ATOMIC_RELAXED, __HIP_MEMORY_SCOPE_AGENT)
#define STA64(p, v) __hip_atomic_store((p), (v), __ATOMIC_RELAXED, __HIP_MEMORY_SCOPE_AGENT)
#define LDA32(p)    __hip_atomic_load((p),  __ATOMIC_RELAXED, __HIP_MEMORY_SCOPE_AGENT)
#define STA32(p, v) __hip_atomic_store((p), (v), __ATOMIC_RELAXED, __HIP_MEMORY_SCOPE_AGENT)

// ===================== PREPASS (unchanged, proven): ig = a @ Wih^T + bias =====================
__global__ __launch_bounds__(192, 2) void ig_prepass_mfma(
    const float* __restrict__ a, const float* __restrict__ Wih,
    const float* __restrict__ bias, char* __restrict__ igbase)
{
    const int gp   = blockIdx.x;
    const int t0   = blockIdx.y * 64;
    const int tid  = threadIdx.x;
    const int lane = tid & 63;
    const int rt   = tid >> 6;

    const int qA = rt, qB = rt + 3;

    short8 afragA[16], afragB[16];
    float biasA[4], biasB[4];
    {
        const float* wrA = &Wih[(size_t)((qA >> 1) * WW + gp * 32 + (qA & 1) * 16 + (lane & 15)) * PP + (lane >> 4) * 8];
        const float* wrB = &Wih[(size_t)((qB >> 1) * WW + gp * 32 + (qB & 1) * 16 + (lane & 15)) * PP + (lane >> 4) * 8];
        #pragma unroll
        for (int s = 0; s < 16; ++s) {
            float ta[8], tb[8];
            *(float4*)&ta[0] = *(const float4*)&wrA[s * 32];
            *(float4*)&ta[4] = *(const float4*)&wrA[s * 32 + 4];
            *(float4*)&tb[0] = *(const float4*)&wrB[s * 32];
            *(float4*)&tb[4] = *(const float4*)&wrB[s * 32 + 4];
            #pragma unroll
            for (int j = 0; j < 8; ++j) { afragA[s][j] = (short)bfround(ta[j]); afragB[s][j] = (short)bfround(tb[j]); }
        }
        #pragma unroll
        for (int r = 0; r < 4; ++r) {
            biasA[r] = bias[(qA >> 1) * WW + gp * 32 + (qA & 1) * 16 + (lane >> 4) * 4 + r];
            biasB[r] = bias[(qB >> 1) * WW + gp * 32 + (qB & 1) * 16 + (lane >> 4) * 4 + r];
        }
    }

    const int bcol = lane & 15;
    const int gA = gp * 2 + (qA & 1), gB = gp * 2 + (qB & 1);
    const int m0A = (qA >> 1) * 16 + (lane >> 4) * 4;
    const int m0B = (qB >> 1) * 16 + (lane >> 4) * 4;

    for (int ct = 0; ct < 128; ++ct) {
        const int tl = ct >> 1, bh = ct & 1;
        const int t  = t0 + tl;
        const int b  = bh * 16 + bcol;
        const float* ap = &a[((size_t)b * TT + t) * PP + (lane >> 4) * 8];
        f32x4 dA = {0.f, 0.f, 0.f, 0.f}, dB = {0.f, 0.f, 0.f, 0.f};
        #pragma unroll 4
        for (int s = 0; s < 16; ++s) {
            float4 lo = *(const float4*)&ap[s * 32];
            float4 hi = *(const float4*)&ap[s * 32 + 4];
            short8 bfv;
            bfv[0] = (short)((__float_as_uint(lo.x) + 0x8000u) >> 16);
            bfv[1] = (short)((__float_as_uint(lo.y) + 0x8000u) >> 16);
            bfv[2] = (short)((__float_as_uint(lo.z) + 0x8000u) >> 16);
            bfv[3] = (short)((__float_as_uint(lo.w) + 0x8000u) >> 16);
            bfv[4] = (short)((__float_as_uint(hi.x) + 0x8000u) >> 16);
            bfv[5] = (short)((__float_as_uint(hi.y) + 0x8000u) >> 16);
            bfv[6] = (short)((__float_as_uint(hi.z) + 0x8000u) >> 16);
            bfv[7] = (short)((__float_as_uint(hi.w) + 0x8000u) >> 16);
            dA = __builtin_amdgcn_mfma_f32_16x16x32_bf16(afragA[s], bfv, dA, 0, 0, 0);
            dB = __builtin_amdgcn_mfma_f32_16x16x32_bf16(afragB[s], bfv, dB, 0, 0, 0);
        }
        u32 loA = bfround(dA[0] + biasA[0]) | (bfround(dA[1] + biasA[1]) << 16);
        u32 hiA = bfround(dA[2] + biasA[2]) | (bfround(dA[3] + biasA[3]) << 16);
        u32 loB = bfround(dB[0] + biasB[0]) | (bfround(dB[1] + biasB[1]) << 16);
        u32 hiB = bfround(dB[2] + biasB[2]) | (bfround(dB[3] + biasB[3]) << 16);
        *(u64*)(igbase + (((size_t)t * 64 + gA) * 1536 + (size_t)b * 48 + m0A) * 2) = (u64)loA | ((u64)hiA << 32);
        *(u64*)(igbase + (((size_t)t * 64 + gB) * 1536 + (size_t)b * 48 + m0B) * 2) = (u64)loB | ((u64)hiB << 32);
    }
}

// ===================== SCAN: barrier-free tagged dataflow =====================
// h published as tagged f32 words: (bf16 << 16) | tag16. Tagged u64 J = 2*i + q
// corresponds to bf16-pack i = k8*64 + 2*b + p (pack holds w = 8k8+4p+{0..3} at b).
// Tags: write h_t -> tb+t (t>0), h_0 -> tb+4097, h_init -> tb+4096.
// Read at step t expects tb+t+1; epilogue expects tb+4097.  tb = (gen&7)*8192.
__global__ __launch_bounds__(768, 1) void gru_scan_df(
    const float* __restrict__ h0, const float* __restrict__ Whh,
    const float* __restrict__ bias_n, const float* __restrict__ Wout,
    const float* __restrict__ bout, const char* __restrict__ igbase,
    float* __restrict__ out, u64* __restrict__ bufA, u64* __restrict__ bufB,
    u32* __restrict__ genp)
{
    __shared__ __align__(16) u64 sh[8192];          // 64 KB staged bf16 h
    __shared__ float sPreH[2][48][34];              // hh partials (stride 34: 2-way free)
    __shared__ float sOutP[4][16][17];              // p3 partials
    __shared__ __align__(8) u64 sIgRaw[2][384];     // ig slice, parity double-buffered

    const int g    = blockIdx.x;                    // 0..63, owns w = g*16..+15
    const int tid  = threadIdx.x;
    const int lane = tid & 63;
    const int wid  = tid >> 6;
    const int rt   = wid >> 2;                      // gate row-tile
    const int bt   = (wid >> 1) & 1;                // b-tile
    const int kh   = wid & 1;                       // k-half

    const u32 gen = LDA32(genp);
    const u32 tb_ = (gen & 7u) * 8192u;

    // ---- loop-invariant Whh A-fragments ----
    short8 afrag[16];
    {
        const float* wr = &Whh[(size_t)(rt * WW + g * 16 + (lane & 15)) * WW + kh * 512 + (lane >> 4) * 8];
        #pragma unroll
        for (int s = 0; s < 16; ++s) {
            float tmp[8];
            *(float4*)&tmp[0] = *(const float4*)&wr[s * 32];
            *(float4*)&tmp[4] = *(const float4*)&wr[s * 32 + 4];
            #pragma unroll
            for (int j = 0; j < 8; ++j) afrag[s][j] = (short)bfround(tmp[j]);
        }
    }
    // ---- Wout A-fragments (waves 0-3) ----
    const int p0  = (g >> 1) * 16;
    const int pb0 = (g & 1) * 16;
    short8 pfrag[8];
    if (wid < 4) {
        const float* wr = &Wout[(size_t)(p0 + (lane & 15)) * WW + (lane >> 4) * 8];
        #pragma unroll
        for (int s = 0; s < 8; ++s) {
            const int k0 = (wid * 8 + s) * 32;
            float tmp[8];
            *(float4*)&tmp[0] = *(const float4*)&wr[k0];
            *(float4*)&tmp[4] = *(const float4*)&wr[k0 + 4];
            #pragma unroll
            for (int j = 0; j < 8; ++j) pfrag[s][j] = (short)bfround(tmp[j]);
        }
    }

    // ---- gate-thread state: tid>=256, m-fast mapping (kills ig LDS conflicts) ----
    float h_own = 0.f, bnv = 0.f;
    int gwl = 0, gb = 0, J32g = 0;
    if (tid >= 256) {
        const int idx = tid - 256;
        gwl = idx & 15;            // hidden-within-slice (fast)
        gb  = idx >> 4;            // batch
        h_own = h0[g * 16 + gwl];
        bnv   = bias_n[g * 16 + gwl];
        const int w_abs = g * 16 + gwl;
        const int i0 = (w_abs >> 3) * 64 + 2 * gb + ((w_abs >> 2) & 1);
        J32g = 4 * i0 + 2 * ((w_abs >> 1) & 1) + (w_abs & 1);
        // publish h_init with tag tb+4096 (consumers poll; no barrier needed)
        STA32(&((u32*)bufA)[J32g], (bfround(h_own) << 16) | ((tb_ + 4096u) & 0xFFFFu));
    }
    float boutp = 0.f;
    if (tid < 256) boutp = bout[p0 + (tid & 15)];

    const short8* shf = (const short8*)sh;
    const int foff = (lane >> 4) * 32 + bt * 16 + (lane & 15);
    const int poff = (lane >> 4) * 32 + pb0 + (lane & 15);

    // ---- tagged staging: poll-load h into sh ----
    auto stage_h = [&](u64* hbuf, u32 rtag) {
        const u64 want = (u64)rtag | ((u64)rtag << 32);
        u64 v[22];
        #pragma unroll
        for (int s = 0; s < 11; ++s) {
            const int i = tid + s * 768;
            if (i < 8192) { v[2*s] = LDA64(&hbuf[2*i]); v[2*s+1] = LDA64(&hbuf[2*i+1]); }
            else          { v[2*s] = want;              v[2*s+1] = want; }
        }
        bool all;
        do {
            all = true;
            #pragma unroll
            for (int s = 0; s < 11; ++s) {
                const int i = tid + s * 768;
                if (i < 8192) {
                    if (((v[2*s]   ^ want) & 0x0000FFFF0000FFFFull) != 0ull) { v[2*s]   = LDA64(&hbuf[2*i]);   all = false; }
                    if (((v[2*s+1] ^ want) & 0x0000FFFF0000FFFFull) != 0ull) { v[2*s+1] = LDA64(&hbuf[2*i+1]); all = false; }
                }
            }
        } while (!all);
        #pragma unroll
        for (int s = 0; s < 11; ++s) {
            const int i = tid + s * 768;
            if (i < 8192) {
                const u64 w0 = v[2*s], w1 = v[2*s+1];
                const u32 lo = (u32)((w0 >> 16) & 0xFFFFu) | (u32)((w0 >> 48) << 16);
                const u32 hi = (u32)((w1 >> 16) & 0xFFFFu) | (u32)((w1 >> 48) << 16);
                sh[i] = (u64)lo | ((u64)hi << 32);
            }
        }
    };

    u64* hcur = bufA;
    u64* hnxt = bufB;

    for (int t = TT - 1; t >= 0; --t) {
        const int par = t & 1;

        // issue ig load early (consumed at gate phase)
        u64 igr = 0;
        if (tid < 384) igr = *(const u64*)(igbase + ((size_t)t * 64 + g) * 3072 + tid * 8);

        stage_h(hcur, (tb_ + (u32)(t + 1)) & 0xFFFFu);
        if (tid < 384) sIgRaw[par][tid] = igr;
        __syncthreads();

        // ---- hh-dot MFMA ----
        {
            f32x4 c0 = {0.f, 0.f, 0.f, 0.f}, c1 = {0.f, 0.f, 0.f, 0.f};
            #pragma unroll
            for (int s = 0; s < 16; s += 2) {
                const int ss = kh * 16 + s;
                short8 b0f = shf[ss * 128 + foff];
                short8 b1f = shf[(ss + 1) * 128 + foff];
                c0 = __builtin_amdgcn_mfma_f32_16x16x32_bf16(afrag[s],     b0f, c0, 0, 0, 0);
                c1 = __builtin_amdgcn_mfma_f32_16x16x32_bf16(afrag[s + 1], b1f, c1, 0, 0, 0);
            }
            c0 = c0 + c1;
            #pragma unroll
            for (int r = 0; r < 4; ++r)
                sPreH[kh][rt * 16 + (lane >> 4) * 4 + r][bt * 16 + (lane & 15)] = c0[r];
        }
        // ---- p3 MFMA for h_{t+1} (waves 0-3) ----
        if (wid < 4 && t < TT - 1) {
            f32x4 d = {0.f, 0.f, 0.f, 0.f};
            #pragma unroll
            for (int s = 0; s < 8; ++s) {
                const int ss = wid * 8 + s;
                short8 bf = shf[ss * 128 + poff];
                d = __builtin_amdgcn_mfma_f32_16x16x32_bf16(pfrag[s], bf, d, 0, 0, 0);
            }
            #pragma unroll
            for (int r = 0; r < 4; ++r)
                sOutP[wid][(lane >> 4) * 4 + r][lane & 15] = d[r];
        }
        __syncthreads();

        // ---- gates (tid>=256) publish tagged h; out store (tid<256) ----
        if (tid >= 256) {
            const unsigned short* sIgU = (const unsigned short*)sIgRaw[par];
            const float ig_r = bf2f(sIgU[gb * 48 + gwl]);
            const float ig_z = bf2f(sIgU[gb * 48 + 16 + gwl]);
            const float ig_n = bf2f(sIgU[gb * 48 + 32 + gwl]);
            const float hg_r = sPreH[0][gwl][gb]      + sPreH[1][gwl][gb];
            const float hg_z = sPreH[0][16 + gwl][gb] + sPreH[1][16 + gwl][gb];
            const float hg_n = sPreH[0][32 + gwl][gb] + sPreH[1][32 + gwl][gb];
            const float rr = __builtin_amdgcn_rcpf(1.f + __expf(-(ig_r + hg_r)));
            const float zz = __builtin_amdgcn_rcpf(1.f + __expf(-(ig_z + hg_z)));
            const float xn = ig_n + rr * (hg_n + bnv);
            const float nn = 2.f * __builtin_amdgcn_rcpf(1.f + __expf(-2.f * xn)) - 1.f;
            h_own = nn + zz * (h_own - nn);
            const u32 wtag = (t > 0) ? (tb_ + (u32)t) : (tb_ + 4097u);
            STA32(&((u32*)hnxt)[J32g], (bfround(h_own) << 16) | (wtag & 0xFFFFu));
        } else if (t < TT - 1) {
            const int p = tid & 15, b = tid >> 4;
            const float s_ = boutp + sOutP[0][p][b] + sOutP[1][p][b]
                                   + sOutP[2][p][b] + sOutP[3][p][b];
            out[((size_t)(pb0 + b) * TT + (t + 1)) * PP + p0 + p] = s_;
        }

        u64* tmp = hcur; hcur = hnxt; hnxt = tmp;
    }

    // ---- epilogue: stage h_0 (tag tb+4097), project -> out[:,0,:] ----
    stage_h(hcur, (tb_ + 4097u) & 0xFFFFu);
    __syncthreads();
    if (wid < 4) {
        f32x4 d = {0.f, 0.f, 0.f, 0.f};
        #pragma unroll
        for (int s = 0; s < 8; ++s) {
            const int ss = wid * 8 + s;
            short8 bf = shf[ss * 128 + poff];
            d = __builtin_amdgcn_mfma_f32_16x16x32_bf16(pfrag[s], bf, d, 0, 0, 0);
        }
        #pragma unroll
        for (int r = 0; r < 4; ++r)
            sOutP[wid][(lane >> 4) * 4 + r][lane & 15] = d[r];
    }
    __syncthreads();
    if (tid < 256) {
        const int p = tid & 15, b = tid >> 4;
        const float s_ = boutp + sOutP[0][p][b] + sOutP[1][p][b]
                               + sOutP[2][p][b] + sOutP[3][p][b];
        out[((size_t)(pb0 + b) * TT) * PP + p0 + p] = s_;
    }

    // advance generation for the next launch (affects only future replays)
    if (g == 0 && tid == 0) STA32(genp, gen + 1u);
}

// ===================== FALLBACK (proven R3 kernel, 256 WGs) =====================
__device__ __forceinline__ void grid_barrier32(u32* leaf, u32* root, u32 rtarget, int g) {
    asm volatile("s_waitcnt vmcnt(0)" ::: "memory");
    __syncthreads();
    if (threadIdx.x == 0) {
        u32 old = __hip_atomic_fetch_add(&leaf[(g & 7) * 16], 1u,
                                         __ATOMIC_RELAXED, __HIP_MEMORY_SCOPE_AGENT);
        if ((old & 31u) == 31u)
            __hip_atomic_fetch_add(root, 1u, __ATOMIC_RELAXED, __HIP_MEMORY_SCOPE_AGENT);
        while (__hip_atomic_load(root, __ATOMIC_RELAXED, __HIP_MEMORY_SCOPE_AGENT) < rtarget)
            __builtin_amdgcn_s_sleep(2);
    }
    __syncthreads();
}

__global__ __launch_bounds__(768, 1) void gru_scan_fb(
    const float* __restrict__ a, const float* __restrict__ h0,
    const float* __restrict__ Wih, const float* __restrict__ Whh,
    const float* __restrict__ bias, const float* __restrict__ bias_n,
    const float* __restrict__ Wout, const float* __restrict__ bout,
    float* __restrict__ out, u64* __restrict__ hbufA, u64* __restrict__ hbufB,
    u32* __restrict__ leaf, u32* __restrict__ root)
{
    __shared__ float sWhh[12][WW];
    __shared__ __align__(16) u64 sh[8192];
    __shared__ float sPreH[2][12][BB];
    __shared__ float sIg[2][2][12][BB];
    __shared__ float sOutPart[12][64];

    const int g   = blockIdx.x;
    const int tid = threadIdx.x;
    const int w0  = g * 4;

    for (int i = tid; i < 12 * (WW / 4); i += 768) {
        int row_ = i / (WW / 4);
        int k4_  = i - row_ * (WW / 4);
        int gr   = (row_ >> 2) * WW + w0 + (row_ & 3);
        *(float4*)&sWhh[row_][k4_ * 4] = *(const float4*)&Whh[(size_t)gr * WW + k4_ * 4];
    }
    const int  half = (tid >= 384) ? 1 : 0;
    const int  sub  = tid - half * 384;
    const int  b1   = sub & 31;
    const int  row  = sub >> 5;
    const int  grow = (row >> 2) * WW + w0 + (row & 3);
    const float biasv = (half == 0) ? bias[grow] : 0.0f;

    float ho0 = 0.f, ho1 = 0.f, ho2 = 0.f, ho3 = 0.f;
    float bn0 = 0.f, bn1 = 0.f, bn2 = 0.f, bn3 = 0.f;
    if (tid < 32) {
        ho0 = h0[w0 + 0]; ho1 = h0[w0 + 1]; ho2 = h0[w0 + 2]; ho3 = h0[w0 + 3];
        bn0 = bias_n[w0 + 0]; bn1 = bias_n[w0 + 1]; bn2 = bias_n[w0 + 2]; bn3 = bias_n[w0 + 3];
        u32 lo = bfround(ho0) | (bfround(ho1) << 16);
        u32 hi = bfround(ho2) | (bfround(ho3) << 16);
        STA64(&hbufA[g * 32 + tid], (u64)lo | ((u64)hi << 32));
    }
    const int  p0  = (g & 31) * 16;
    const int  b0  = (g >> 5) * 4;
    const int  o   = tid & 63;
    const int  c   = tid >> 6;
    const int  p3p = p0 + (o & 15);
    const int  p3b = b0 + (o >> 4);
    const float boutv = bout[p3p];

    auto ihdot = [&](int t_, int pbuf) {
        const float4* __restrict__ arow = (const float4*)&a[((size_t)b1 * TT + t_) * PP];
        const float4* __restrict__ wrow = (const float4*)&Wih[(size_t)grow * PP];
        const int p40 = half * 64;
        float4 acc = {0.f, 0.f, 0.f, 0.f};
        #pragma unroll 8
        for (int p4 = 0; p4 < 64; ++p4) {
            float4 av = arow[p40 + p4];
            float4 wv = wrow[p40 + p4];
            acc.x += av.x * wv.x; acc.y += av.y * wv.y;
            acc.z += av.z * wv.z; acc.w += av.w * wv.w;
        }
        sIg[pbuf][half][row][b1] = (acc.x + acc.y) + (acc.z + acc.w) + biasv;
    };
    auto p3partials = [&]() {
        const float4* __restrict__ wrow = (const float4*)&Wout[(size_t)p3p * WW];
        float4 acc = {0.f, 0.f, 0.f, 0.f};
        for (int k4 = c; k4 < WW / 4; k4 += 12) {
            u64 pk = sh[k4 * 32 + p3b];
            float4 wv = wrow[k4];
            acc.x += bflo((u32)pk) * wv.x;
            acc.y += bfhi((u32)pk) * wv.y;
            acc.z += bflo((u32)(pk >> 32)) * wv.z;
            acc.w += bfhi((u32)(pk >> 32)) * wv.w;
        }
        sOutPart[c][o] = (acc.x + acc.y) + (acc.z + acc.w);
    };

    ihdot(TT - 1, 1);
    u32 rtarget = 8;
    grid_barrier32(leaf, root, rtarget, g);
    u64* hcur = hbufA;
    u64* hnxt = hbufB;

    for (int t = TT - 1; t >= 0; --t) {
        const int par = t & 1;
        u64 r0, r1, r2, r3, r4, r5, r6, r7, r8, r9, r10 = 0;
        #define LDH(J) LDA64(&hcur[tid + (J) * 768])
        r0 = LDH(0); r1 = LDH(1); r2 = LDH(2); r3 = LDH(3); r4 = LDH(4);
        r5 = LDH(5); r6 = LDH(6); r7 = LDH(7); r8 = LDH(8); r9 = LDH(9);
        if (tid < 512) r10 = LDH(10);
        #undef LDH
        if (t > 0) ihdot(t - 1, par ^ 1);
        sh[tid] = r0;          sh[tid + 768] = r1;   sh[tid + 1536] = r2;
        sh[tid + 2304] = r3;   sh[tid + 3072] = r4;  sh[tid + 3840] = r5;
        sh[tid + 4608] = r6;   sh[tid + 5376] = r7;  sh[tid + 6144] = r8;
        sh[tid + 6912] = r9;
        if (tid < 512) sh[tid + 7680] = r10;
        __syncthreads();
        {
            const int k40 = half * 128;
            float4 acc = {0.f, 0.f, 0.f, 0.f};
            #pragma unroll 4
            for (int k4 = 0; k4 < 128; ++k4) {
                u64 pk = sh[(k40 + k4) * 32 + b1];
                float4 wv = *(const float4*)&sWhh[row][(k40 + k4) * 4];
                acc.x += bflo((u32)pk) * wv.x;
                acc.y += bfhi((u32)pk) * wv.y;
                acc.z += bflo((u32)(pk >> 32)) * wv.z;
                acc.w += bfhi((u32)(pk >> 32)) * wv.w;
            }
            sPreH[half][row][b1] = (acc.x + acc.y) + (acc.z + acc.w);
        }
        if (t < TT - 1) p3partials();
        __syncthreads();
        if (tid < 32) {
            const int b = tid;
            float hn0, hn1, hn2, hn3;
            {
                float rr = 1.f / (1.f + __expf(-(sIg[par][0][0][b] + sIg[par][1][0][b] + sPreH[0][0][b] + sPreH[1][0][b])));
                float zz = 1.f / (1.f + __expf(-(sIg[par][0][4][b] + sIg[par][1][4][b] + sPreH[0][4][b] + sPreH[1][4][b])));
                float nn = tanhf(sIg[par][0][8][b] + sIg[par][1][8][b] + rr * (sPreH[0][8][b] + sPreH[1][8][b] + bn0));
                hn0 = nn + zz * (ho0 - nn); ho0 = hn0;
            }
            {
                float rr = 1.f / (1.f + __expf(-(sIg[par][0][1][b] + sIg[par][1][1][b] + sPreH[0][1][b] + sPreH[1][1][b])));
                float zz = 1.f / (1.f + __expf(-(sIg[par][0][5][b] + sIg[par][1][5][b] + sPreH[0][5][b] + sPreH[1][5][b])));
                float nn = tanhf(sIg[par][0][9][b] + sIg[par][1][9][b] + rr * (sPreH[0][9][b] + sPreH[1][9][b] + bn1));
                hn1 = nn + zz * (ho1 - nn); ho1 = hn1;
            }
            {
                float rr = 1.f / (1.f + __expf(-(sIg[par][0][2][b] + sIg[par][1][2][b] + sPreH[0][2][b] + sPreH[1][2][b])));
                float zz = 1.f / (1.f + __expf(-(sIg[par][0][6][b] + sIg[par][1][6][b] + sPreH[0][6][b] + sPreH[1][6][b])));
                float nn = tanhf(sIg[par][0][10][b] + sIg[par][1][10][b] + rr * (sPreH[0][10][b] + sPreH[1][10][b] + bn2));
                hn2 = nn + zz * (ho2 - nn); ho2 = hn2;
            }
            {
                float rr = 1.f / (1.f + __expf(-(sIg[par][0][3][b] + sIg[par][1][3][b] + sPreH[0][3][b] + sPreH[1][3][b])));
                float zz = 1.f / (1.f + __expf(-(sIg[par][0][7][b] + sIg[par][1][7][b] + sPreH[0][7][b] + sPreH[1][7][b])));
                float nn = tanhf(sIg[par][0][11][b] + sIg[par][1][11][b] + rr * (sPreH[0][11][b] + sPreH[1][11][b] + bn3));
                hn3 = nn + zz * (ho3 - nn); ho3 = hn3;
            }
            u32 lo = bfround(hn0) | (bfround(hn1) << 16);
            u32 hi = bfround(hn2) | (bfround(hn3) << 16);
            STA64(&hnxt[g * 32 + tid], (u64)lo | ((u64)hi << 32));
        }
        if (t < TT - 1 && tid < 64) {
            float s_ = boutv;
            #pragma unroll
            for (int cc = 0; cc < 12; ++cc) s_ += sOutPart[cc][o];
            out[((size_t)p3b * TT + (t + 1)) * PP + p3p] = s_;
        }
        rtarget += 8;
        grid_barrier32(leaf, root, rtarget, g);
        u64* tmp = hcur; hcur = hnxt; hnxt = tmp;
    }
    {
        u64 r0, r1, r2, r3, r4, r5, r6, r7, r8, r9, r10 = 0;
        #define LDH(J) LDA64(&hcur[tid + (J) * 768])
        r0 = LDH(0); r1 = LDH(1); r2 = LDH(2); r3 = LDH(3); r4 = LDH(4);
        r5 = LDH(5); r6 = LDH(6); r7 = LDH(7); r8 = LDH(8); r9 = LDH(9);
        if (tid < 512) r10 = LDH(10);
        #undef LDH
        sh[tid] = r0;          sh[tid + 768] = r1;   sh[tid + 1536] = r2;
        sh[tid + 2304] = r3;   sh[tid + 3072] = r4;  sh[tid + 3840] = r5;
        sh[tid + 4608] = r6;   sh[tid + 5376] = r7;  sh[tid + 6144] = r8;
        sh[tid + 6912] = r9;
        if (tid < 512) sh[tid + 7680] = r10;
        __syncthreads();
        p3partials();
        __syncthreads();
        if (tid < 64) {
            float s_ = boutv;
            #pragma unroll
            for (int cc = 0; cc < 12; ++cc) s_ += sOutPart[cc][o];
            out[((size_t)p3b * TT) * PP + p3p] = s_;
        }
    }
}

extern "C" void kernel_launch(void* const* d_in, const int* in_sizes, int n_in,
                              void* d_out, int out_size, void* d_ws, size_t ws_size,
                              hipStream_t stream) {
    const float* a      = (const float*)d_in[0];
    const float* h0     = (const float*)d_in[1];
    const float* Wih    = (const float*)d_in[2];
    const float* Whh    = (const float*)d_in[3];
    const float* bias   = (const float*)d_in[4];
    const float* bias_n = (const float*)d_in[5];
    const float* Wout   = (const float*)d_in[6];
    const float* bout   = (const float*)d_in[7];
    float* out = (float*)d_out;

    const size_t IG_BYTES = (size_t)TT * 64 * 3072;          // 805,306,368
    const size_t NEED     = IG_BYTES + 2 * 131072 + 64;

    if (ws_size >= NEED) {
        char* igbase = (char*)d_ws;
        u64*  bufA = (u64*)((char*)d_ws + IG_BYTES);          // 16384 u64 tagged
        u64*  bufB = bufA + 16384;
        u32*  genp = (u32*)((char*)d_ws + IG_BYTES + 2 * 131072);
        hipLaunchKernelGGL(ig_prepass_mfma, dim3(32, 64), dim3(192), 0, stream,
                           a, Wih, bias, igbase);
        void* args[] = {(void*)&h0, (void*)&Whh, (void*)&bias_n, (void*)&Wout,
                        (void*)&bout, (void*)&igbase, (void*)&out,
                        (void*)&bufA, (void*)&bufB, (void*)&genp};
        hipLaunchCooperativeKernel((void*)gru_scan_df, dim3(64), dim3(768),
                                   args, 0, stream);
    } else {
        u64* hA   = (u64*)d_ws;
        u64* hB   = hA + 8192;
        u32* leaf = (u32*)((char*)d_ws + 2 * 65536);
        u32* root = leaf + 8 * 16;
        hipMemsetAsync(leaf, 0, 1024, stream);
        void* args[] = {(void*)&a, (void*)&h0, (void*)&Wih, (void*)&Whh,
                        (void*)&bias, (void*)&bias_n, (void*)&Wout, (void*)&bout,
                        (void*)&out, (void*)&hA, (void*)&hB, (void*)&leaf, (void*)&root};
        hipLaunchCooperativeKernel((void*)gru_scan_fb, dim3(256), dim3(768),
                                   args, 0, stream);
    }
}

// Round 7
// 24545.956 us; speedup vs baseline: 1.2444x; 1.2444x over previous
//
#include <hip/hip_runtime.h>
#include <cstddef>

#define BB 32
#define TT 4096
#define PP 512
#define WW 1024

using u32 = unsigned;
using u64 = unsigned long long;
using u16 = unsigned short;

typedef short short8 __attribute__((ext_vector_type(8)));
typedef float f32x4 __attribute__((ext_vector_type(4)));

__device__ __forceinline__ u32 bfround(float f) {
    u32 u = __float_as_uint(f);
    return (u + 0x7fffu + ((u >> 16) & 1u)) >> 16;
}
__device__ __forceinline__ float bf2f(u32 q) { return __uint_as_float(q << 16); }
__device__ __forceinline__ float bflo(u32 q) { return __uint_as_float(q << 16); }
__device__ __forceinline__ float bfhi(u32 q) { return __uint_as_float(q & 0xffff0000u); }

#define LDA64(p)    __hip_atomic_load((p),  __ATOMIC_RELAXED, __HIP_MEMORY_SCOPE_AGENT)
#define STA64(p, v) __hip_atomic_store((p), (v), __ATOMIC_RELAXED, __HIP_MEMORY_SCOPE_AGENT)
#define LDA32(p)    __hip_atomic_load((p),  __ATOMIC_RELAXED, __HIP_MEMORY_SCOPE_AGENT)
#define STA32(p, v) __hip_atomic_store((p), (v), __ATOMIC_RELAXED, __HIP_MEMORY_SCOPE_AGENT)
#define STA16(p, v) __hip_atomic_store((p), (v), __ATOMIC_RELAXED, __HIP_MEMORY_SCOPE_AGENT)

// ============ PREPASS v2: 12-wave blocks, 192 rows each, 16 gp-blocks ============
// ig layout: u16[((t*64 + gWG)*32 + b)*48 + slot], slot = gate*16 + (w&15)
__global__ __launch_bounds__(768, 1) void ig_prepass16(
    const float* __restrict__ a, const float* __restrict__ Wih,
    const float* __restrict__ bias, char* __restrict__ igbase)
{
    const int gp   = blockIdx.x;          // 0..15
    const int t0   = blockIdx.y * 64;     // 64 t-blocks
    const int tid  = threadIdx.x;
    const int lane = tid & 63;
    const int wid  = tid >> 6;            // 0..11, one 16-row tile each
    const int growb = gp * 192 + wid * 16;

    short8 afrag[16];
    float  biasv[4];
    {
        const float* wr = &Wih[(size_t)(growb + (lane & 15)) * PP + (lane >> 4) * 8];
        #pragma unroll
        for (int s = 0; s < 16; ++s) {
            float t8[8];
            *(float4*)&t8[0] = *(const float4*)&wr[s * 32];
            *(float4*)&t8[4] = *(const float4*)&wr[s * 32 + 4];
            #pragma unroll
            for (int j = 0; j < 8; ++j) afrag[s][j] = (short)bfround(t8[j]);
        }
        #pragma unroll
        for (int r = 0; r < 4; ++r) biasv[r] = bias[growb + (lane >> 4) * 4 + r];
    }
    const int grow0 = growb + (lane >> 4) * 4;
    const int gate  = grow0 >> 10;
    const int w     = grow0 & 1023;
    const int gWG   = w >> 4;
    const int slot  = gate * 16 + (w & 15);
    const int bcol  = lane & 15;

    for (int ct = 0; ct < 128; ++ct) {
        const int t = t0 + (ct >> 1);
        const int b = (ct & 1) * 16 + bcol;
        const float* ap = &a[((size_t)b * TT + t) * PP + (lane >> 4) * 8];
        f32x4 d = {0.f, 0.f, 0.f, 0.f};
        #pragma unroll 4
        for (int s = 0; s < 16; ++s) {
            float4 lo = *(const float4*)&ap[s * 32];
            float4 hi = *(const float4*)&ap[s * 32 + 4];
            short8 bfv;
            bfv[0] = (short)((__float_as_uint(lo.x) + 0x8000u) >> 16);
            bfv[1] = (short)((__float_as_uint(lo.y) + 0x8000u) >> 16);
            bfv[2] = (short)((__float_as_uint(lo.z) + 0x8000u) >> 16);
            bfv[3] = (short)((__float_as_uint(lo.w) + 0x8000u) >> 16);
            bfv[4] = (short)((__float_as_uint(hi.x) + 0x8000u) >> 16);
            bfv[5] = (short)((__float_as_uint(hi.y) + 0x8000u) >> 16);
            bfv[6] = (short)((__float_as_uint(hi.z) + 0x8000u) >> 16);
            bfv[7] = (short)((__float_as_uint(hi.w) + 0x8000u) >> 16);
            d = __builtin_amdgcn_mfma_f32_16x16x32_bf16(afrag[s], bfv, d, 0, 0, 0);
        }
        u32 lo32 = bfround(d[0] + biasv[0]) | (bfround(d[1] + biasv[1]) << 16);
        u32 hi32 = bfround(d[2] + biasv[2]) | (bfround(d[3] + biasv[3]) << 16);
        *(u64*)(igbase + (((size_t)t * 64 + gWG) * 1536 + (size_t)b * 48 + slot) * 2) =
            (u64)lo32 | ((u64)hi32 << 32);
    }
}

// ============ SCAN v3: flag-array barrier, deferred out, 8-wave P3 ============
__global__ __launch_bounds__(768, 1) void gru_scan3(
    const float* __restrict__ h0, const float* __restrict__ Whh,
    const float* __restrict__ bias_n, const float* __restrict__ Wout,
    const float* __restrict__ bout, const char* __restrict__ igbase,
    float* __restrict__ out, u64* __restrict__ bufA, u64* __restrict__ bufB,
    u32* __restrict__ flags)
{
    __shared__ __align__(16) u64 sh[8192];          // 64 KB staged bf16 h
    __shared__ float sPreH[2][48][34];
    __shared__ float sOutP[8][16][17];
    __shared__ __align__(8) u64 sIgRaw[384];

    const int g    = blockIdx.x;                    // 0..63, owns w = g*16..+15
    const int tid  = threadIdx.x;
    const int lane = tid & 63;
    const int wid  = tid >> 6;
    const int rt   = wid >> 2;
    const int bt   = (wid >> 1) & 1;
    const int kh   = wid & 1;

    // Whh A-fragments (loop-invariant)
    short8 afrag[16];
    {
        const float* wr = &Whh[(size_t)(rt * WW + g * 16 + (lane & 15)) * WW + kh * 512 + (lane >> 4) * 8];
        #pragma unroll
        for (int s = 0; s < 16; ++s) {
            float t8[8];
            *(float4*)&t8[0] = *(const float4*)&wr[s * 32];
            *(float4*)&t8[4] = *(const float4*)&wr[s * 32 + 4];
            #pragma unroll
            for (int j = 0; j < 8; ++j) afrag[s][j] = (short)bfround(t8[j]);
        }
    }
    // Wout A-fragments: waves 4..11, 4 kslices each (covers all 32)
    const int p0  = (g >> 1) * 16;
    const int pb0 = (g & 1) * 16;
    short8 pfrag[4];
    if (wid >= 4) {
        const float* wr = &Wout[(size_t)(p0 + (lane & 15)) * WW + (lane >> 4) * 8];
        #pragma unroll
        for (int s = 0; s < 4; ++s) {
            const int k0 = ((wid - 4) * 4 + s) * 32;
            float t8[8];
            *(float4*)&t8[0] = *(const float4*)&wr[k0];
            *(float4*)&t8[4] = *(const float4*)&wr[k0 + 4];
            #pragma unroll
            for (int j = 0; j < 8; ++j) pfrag[s][j] = (short)bfround(t8[j]);
        }
    }

    // gate-thread state (tid>=256): one (w,b) each, direct u16 publish
    float h_own = 0.f, bnv = 0.f;
    int gwl = 0, gb = 0; u32 hidx16 = 0;
    if (tid >= 256) {
        const int idx = tid - 256;
        gwl = idx & 15; gb = idx >> 4;
        h_own = h0[g * 16 + gwl];
        bnv   = bias_n[g * 16 + gwl];
        const int w_abs = g * 16 + gwl;
        const int ip = (w_abs >> 3) * 64 + 2 * gb + ((w_abs >> 2) & 1);
        hidx16 = 4 * ip + (w_abs & 3);
        STA16(&((u16*)bufA)[hidx16], (u16)bfround(h_own));   // publish h_init
    }
    const float boutp = (tid < 256) ? bout[p0 + (tid & 15)] : 0.f;

    const short8* shf = (const short8*)sh;
    const int foff = (lane >> 4) * 32 + bt * 16 + (lane & 15);
    const int poff = (lane >> 4) * 32 + pb0 + (lane & 15);

    u64* hcur = bufA;
    u64* hnxt = bufB;
    u32 kk = 1;

    // flat flag-array barrier: own-line store, wave0 polls 64 distinct lines
    auto gbar = [&](u32 want) {
        asm volatile("s_waitcnt vmcnt(0)" ::: "memory");   // per-wave publish drain
        __syncthreads();
        if (tid == 0) STA32(&flags[g * 16], want);
        if (tid < 64) {
            for (;;) {
                u32 v = LDA32(&flags[tid * 16]);
                if (__all((tid == g) || ((int)(v - want) >= 0))) break;
                __builtin_amdgcn_s_sleep(1);
            }
        }
        __syncthreads();
    };
    gbar(kk); ++kk;   // h_init visible

    for (int t = TT - 1; t >= 0; --t) {
        // ---- deferred out[t+2] store (in h-load shadow, off the drain path) ----
        if (t < TT - 2 && tid < 256) {
            const int p = tid & 15, b = tid >> 4;
            float s_ = boutp;
            #pragma unroll
            for (int cc = 0; cc < 8; ++cc) s_ += sOutP[cc][p][b];
            out[((size_t)(pb0 + b) * TT + (t + 2)) * PP + p0 + p] = s_;
        }
        // ---- stage h + ig ----
        u64 r0, r1, r2, r3, r4, r5, r6, r7, r8, r9, r10 = 0;
        #define LDH(J) LDA64(&hcur[tid + (J) * 768])
        r0 = LDH(0); r1 = LDH(1); r2 = LDH(2); r3 = LDH(3); r4 = LDH(4);
        r5 = LDH(5); r6 = LDH(6); r7 = LDH(7); r8 = LDH(8); r9 = LDH(9);
        if (tid < 512) r10 = LDH(10);
        #undef LDH
        u64 igr = 0;
        if (tid < 384) igr = *(const u64*)(igbase + ((size_t)t * 64 + g) * 3072 + tid * 8);

        sh[tid] = r0;          sh[tid + 768] = r1;   sh[tid + 1536] = r2;
        sh[tid + 2304] = r3;   sh[tid + 3072] = r4;  sh[tid + 3840] = r5;
        sh[tid + 4608] = r6;   sh[tid + 5376] = r7;  sh[tid + 6144] = r8;
        sh[tid + 6912] = r9;
        if (tid < 512) sh[tid + 7680] = r10;
        if (tid < 384) sIgRaw[tid] = igr;
        __syncthreads();

        // ---- hh-dot MFMA (all 12 waves) ----
        {
            f32x4 c0 = {0.f, 0.f, 0.f, 0.f}, c1 = {0.f, 0.f, 0.f, 0.f};
            #pragma unroll
            for (int s = 0; s < 16; s += 2) {
                const int ss = kh * 16 + s;
                short8 b0f = shf[ss * 128 + foff];
                short8 b1f = shf[(ss + 1) * 128 + foff];
                c0 = __builtin_amdgcn_mfma_f32_16x16x32_bf16(afrag[s],     b0f, c0, 0, 0, 0);
                c1 = __builtin_amdgcn_mfma_f32_16x16x32_bf16(afrag[s + 1], b1f, c1, 0, 0, 0);
            }
            c0 = c0 + c1;
            #pragma unroll
            for (int r = 0; r < 4; ++r)
                sPreH[kh][rt * 16 + (lane >> 4) * 4 + r][bt * 16 + (lane & 15)] = c0[r];
        }
        // ---- P3 MFMA for h_{t+1}: waves 4..11, 4 kslices each ----
        if (wid >= 4 && t < TT - 1) {
            f32x4 d = {0.f, 0.f, 0.f, 0.f};
            #pragma unroll
            for (int s = 0; s < 4; ++s) {
                const int ss = (wid - 4) * 4 + s;
                d = __builtin_amdgcn_mfma_f32_16x16x32_bf16(pfrag[s], shf[ss * 128 + poff], d, 0, 0, 0);
            }
            #pragma unroll
            for (int r = 0; r < 4; ++r)
                sOutP[wid - 4][(lane >> 4) * 4 + r][lane & 15] = d[r];
        }
        __syncthreads();

        // ---- gates: compute + direct u16 publish ----
        if (tid >= 256) {
            const u16* sIgU = (const u16*)sIgRaw;
            const float ig_r = bf2f(sIgU[gb * 48 + gwl]);
            const float ig_z = bf2f(sIgU[gb * 48 + 16 + gwl]);
            const float ig_n = bf2f(sIgU[gb * 48 + 32 + gwl]);
            const float hg_r = sPreH[0][gwl][gb]      + sPreH[1][gwl][gb];
            const float hg_z = sPreH[0][16 + gwl][gb] + sPreH[1][16 + gwl][gb];
            const float hg_n = sPreH[0][32 + gwl][gb] + sPreH[1][32 + gwl][gb];
            const float rr = __builtin_amdgcn_rcpf(1.f + __expf(-(ig_r + hg_r)));
            const float zz = __builtin_amdgcn_rcpf(1.f + __expf(-(ig_z + hg_z)));
            const float xn = ig_n + rr * (hg_n + bnv);
            const float nn = 2.f * __builtin_amdgcn_rcpf(1.f + __expf(-2.f * xn)) - 1.f;
            h_own = nn + zz * (h_own - nn);
            STA16(&((u16*)hnxt)[hidx16], (u16)bfround(h_own));
        }

        gbar(kk); ++kk;
        u64* tmp = hcur; hcur = hnxt; hnxt = tmp;
    }

    // ---- epilogue: out[1] from S(0)'s P3, then stage h_0 -> out[0] ----
    if (tid < 256) {
        const int p = tid & 15, b = tid >> 4;
        float s_ = boutp;
        #pragma unroll
        for (int cc = 0; cc < 8; ++cc) s_ += sOutP[cc][p][b];
        out[((size_t)(pb0 + b) * TT + 1) * PP + p0 + p] = s_;
    }
    {
        u64 r0, r1, r2, r3, r4, r5, r6, r7, r8, r9, r10 = 0;
        #define LDH(J) LDA64(&hcur[tid + (J) * 768])
        r0 = LDH(0); r1 = LDH(1); r2 = LDH(2); r3 = LDH(3); r4 = LDH(4);
        r5 = LDH(5); r6 = LDH(6); r7 = LDH(7); r8 = LDH(8); r9 = LDH(9);
        if (tid < 512) r10 = LDH(10);
        #undef LDH
        sh[tid] = r0;          sh[tid + 768] = r1;   sh[tid + 1536] = r2;
        sh[tid + 2304] = r3;   sh[tid + 3072] = r4;  sh[tid + 3840] = r5;
        sh[tid + 4608] = r6;   sh[tid + 5376] = r7;  sh[tid + 6144] = r8;
        sh[tid + 6912] = r9;
        if (tid < 512) sh[tid + 7680] = r10;
        __syncthreads();
        if (wid >= 4) {
            f32x4 d = {0.f, 0.f, 0.f, 0.f};
            #pragma unroll
            for (int s = 0; s < 4; ++s) {
                const int ss = (wid - 4) * 4 + s;
                d = __builtin_amdgcn_mfma_f32_16x16x32_bf16(pfrag[s], shf[ss * 128 + poff], d, 0, 0, 0);
            }
            #pragma unroll
            for (int r = 0; r < 4; ++r)
                sOutP[wid - 4][(lane >> 4) * 4 + r][lane & 15] = d[r];
        }
        __syncthreads();
        if (tid < 256) {
            const int p = tid & 15, b = tid >> 4;
            float s_ = boutp;
            #pragma unroll
            for (int cc = 0; cc < 8; ++cc) s_ += sOutP[cc][p][b];
            out[((size_t)(pb0 + b) * TT) * PP + p0 + p] = s_;
        }
    }
}

// ===================== FALLBACK (proven R3 kernel, 256 WGs) =====================
__device__ __forceinline__ void grid_barrier32(u32* leaf, u32* root, u32 rtarget, int g) {
    asm volatile("s_waitcnt vmcnt(0)" ::: "memory");
    __syncthreads();
    if (threadIdx.x == 0) {
        u32 old = __hip_atomic_fetch_add(&leaf[(g & 7) * 16], 1u,
                                         __ATOMIC_RELAXED, __HIP_MEMORY_SCOPE_AGENT);
        if ((old & 31u) == 31u)
            __hip_atomic_fetch_add(root, 1u, __ATOMIC_RELAXED, __HIP_MEMORY_SCOPE_AGENT);
        while (__hip_atomic_load(root, __ATOMIC_RELAXED, __HIP_MEMORY_SCOPE_AGENT) < rtarget)
            __builtin_amdgcn_s_sleep(2);
    }
    __syncthreads();
}

__global__ __launch_bounds__(768, 1) void gru_scan_fb(
    const float* __restrict__ a, const float* __restrict__ h0,
    const float* __restrict__ Wih, const float* __restrict__ Whh,
    const float* __restrict__ bias, const float* __restrict__ bias_n,
    const float* __restrict__ Wout, const float* __restrict__ bout,
    float* __restrict__ out, u64* __restrict__ hbufA, u64* __restrict__ hbufB,
    u32* __restrict__ leaf, u32* __restrict__ root)
{
    __shared__ float sWhh[12][WW];
    __shared__ __align__(16) u64 sh[8192];
    __shared__ float sPreH[2][12][BB];
    __shared__ float sIg[2][2][12][BB];
    __shared__ float sOutPart[12][64];

    const int g   = blockIdx.x;
    const int tid = threadIdx.x;
    const int w0  = g * 4;

    for (int i = tid; i < 12 * (WW / 4); i += 768) {
        int row_ = i / (WW / 4);
        int k4_  = i - row_ * (WW / 4);
        int gr   = (row_ >> 2) * WW + w0 + (row_ & 3);
        *(float4*)&sWhh[row_][k4_ * 4] = *(const float4*)&Whh[(size_t)gr * WW + k4_ * 4];
    }
    const int  half = (tid >= 384) ? 1 : 0;
    const int  sub  = tid - half * 384;
    const int  b1   = sub & 31;
    const int  row  = sub >> 5;
    const int  grow = (row >> 2) * WW + w0 + (row & 3);
    const float biasv = (half == 0) ? bias[grow] : 0.0f;

    float ho0 = 0.f, ho1 = 0.f, ho2 = 0.f, ho3 = 0.f;
    float bn0 = 0.f, bn1 = 0.f, bn2 = 0.f, bn3 = 0.f;
    if (tid < 32) {
        ho0 = h0[w0 + 0]; ho1 = h0[w0 + 1]; ho2 = h0[w0 + 2]; ho3 = h0[w0 + 3];
        bn0 = bias_n[w0 + 0]; bn1 = bias_n[w0 + 1]; bn2 = bias_n[w0 + 2]; bn3 = bias_n[w0 + 3];
        u32 lo = bfround(ho0) | (bfround(ho1) << 16);
        u32 hi = bfround(ho2) | (bfround(ho3) << 16);
        STA64(&hbufA[g * 32 + tid], (u64)lo | ((u64)hi << 32));
    }
    const int  p0  = (g & 31) * 16;
    const int  b0  = (g >> 5) * 4;
    const int  o   = tid & 63;
    const int  c   = tid >> 6;
    const int  p3p = p0 + (o & 15);
    const int  p3b = b0 + (o >> 4);
    const float boutv = bout[p3p];

    auto ihdot = [&](int t_, int pbuf) {
        const float4* __restrict__ arow = (const float4*)&a[((size_t)b1 * TT + t_) * PP];
        const float4* __restrict__ wrow = (const float4*)&Wih[(size_t)grow * PP];
        const int p40 = half * 64;
        float4 acc = {0.f, 0.f, 0.f, 0.f};
        #pragma unroll 8
        for (int p4 = 0; p4 < 64; ++p4) {
            float4 av = arow[p40 + p4];
            float4 wv = wrow[p40 + p4];
            acc.x += av.x * wv.x; acc.y += av.y * wv.y;
            acc.z += av.z * wv.z; acc.w += av.w * wv.w;
        }
        sIg[pbuf][half][row][b1] = (acc.x + acc.y) + (acc.z + acc.w) + biasv;
    };
    auto p3partials = [&]() {
        const float4* __restrict__ wrow = (const float4*)&Wout[(size_t)p3p * WW];
        float4 acc = {0.f, 0.f, 0.f, 0.f};
        for (int k4 = c; k4 < WW / 4; k4 += 12) {
            u64 pk = sh[k4 * 32 + p3b];
            float4 wv = wrow[k4];
            acc.x += bflo((u32)pk) * wv.x;
            acc.y += bfhi((u32)pk) * wv.y;
            acc.z += bflo((u32)(pk >> 32)) * wv.z;
            acc.w += bfhi((u32)(pk >> 32)) * wv.w;
        }
        sOutPart[c][o] = (acc.x + acc.y) + (acc.z + acc.w);
    };

    ihdot(TT - 1, 1);
    u32 rtarget = 8;
    grid_barrier32(leaf, root, rtarget, g);
    u64* hcur = hbufA;
    u64* hnxt = hbufB;

    for (int t = TT - 1; t >= 0; --t) {
        const int par = t & 1;
        u64 r0, r1, r2, r3, r4, r5, r6, r7, r8, r9, r10 = 0;
        #define LDH(J) LDA64(&hcur[tid + (J) * 768])
        r0 = LDH(0); r1 = LDH(1); r2 = LDH(2); r3 = LDH(3); r4 = LDH(4);
        r5 = LDH(5); r6 = LDH(6); r7 = LDH(7); r8 = LDH(8); r9 = LDH(9);
        if (tid < 512) r10 = LDH(10);
        #undef LDH
        if (t > 0) ihdot(t - 1, par ^ 1);
        sh[tid] = r0;          sh[tid + 768] = r1;   sh[tid + 1536] = r2;
        sh[tid + 2304] = r3;   sh[tid + 3072] = r4;  sh[tid + 3840] = r5;
        sh[tid + 4608] = r6;   sh[tid + 5376] = r7;  sh[tid + 6144] = r8;
        sh[tid + 6912] = r9;
        if (tid < 512) sh[tid + 7680] = r10;
        __syncthreads();
        {
            const int k40 = half * 128;
            float4 acc = {0.f, 0.f, 0.f, 0.f};
            #pragma unroll 4
            for (int k4 = 0; k4 < 128; ++k4) {
                u64 pk = sh[(k40 + k4) * 32 + b1];
                float4 wv = *(const float4*)&sWhh[row][(k40 + k4) * 4];
                acc.x += bflo((u32)pk) * wv.x;
                acc.y += bfhi((u32)pk) * wv.y;
                acc.z += bflo((u32)(pk >> 32)) * wv.z;
                acc.w += bfhi((u32)(pk >> 32)) * wv.w;
            }
            sPreH[half][row][b1] = (acc.x + acc.y) + (acc.z + acc.w);
        }
        if (t < TT - 1) p3partials();
        __syncthreads();
        if (tid < 32) {
            const int b = tid;
            float hn0, hn1, hn2, hn3;
            {
                float rr = 1.f / (1.f + __expf(-(sIg[par][0][0][b] + sIg[par][1][0][b] + sPreH[0][0][b] + sPreH[1][0][b])));
                float zz = 1.f / (1.f + __expf(-(sIg[par][0][4][b] + sIg[par][1][4][b] + sPreH[0][4][b] + sPreH[1][4][b])));
                float nn = tanhf(sIg[par][0][8][b] + sIg[par][1][8][b] + rr * (sPreH[0][8][b] + sPreH[1][8][b] + bn0));
                hn0 = nn + zz * (ho0 - nn); ho0 = hn0;
            }
            {
                float rr = 1.f / (1.f + __expf(-(sIg[par][0][1][b] + sIg[par][1][1][b] + sPreH[0][1][b] + sPreH[1][1][b])));
                float zz = 1.f / (1.f + __expf(-(sIg[par][0][5][b] + sIg[par][1][5][b] + sPreH[0][5][b] + sPreH[1][5][b])));
                float nn = tanhf(sIg[par][0][9][b] + sIg[par][1][9][b] + rr * (sPreH[0][9][b] + sPreH[1][9][b] + bn1));
                hn1 = nn + zz * (ho1 - nn); ho1 = hn1;
            }
            {
                float rr = 1.f / (1.f + __expf(-(sIg[par][0][2][b] + sIg[par][1][2][b] + sPreH[0][2][b] + sPreH[1][2][b])));
                float zz = 1.f / (1.f + __expf(-(sIg[par][0][6][b] + sIg[par][1][6][b] + sPreH[0][6][b] + sPreH[1][6][b])));
                float nn = tanhf(sIg[par][0][10][b] + sIg[par][1][10][b] + rr * (sPreH[0][10][b] + sPreH[1][10][b] + bn2));
                hn2 = nn + zz * (ho2 - nn); ho2 = hn2;
            }
            {
                float rr = 1.f / (1.f + __expf(-(sIg[par][0][3][b] + sIg[par][1][3][b] + sPreH[0][3][b] + sPreH[1][3][b])));
                float zz = 1.f / (1.f + __expf(-(sIg[par][0][7][b] + sIg[par][1][7][b] + sPreH[0][7][b] + sPreH[1][7][b])));
                float nn = tanhf(sIg[par][0][11][b] + sIg[par][1][11][b] + rr * (sPreH[0][11][b] + sPreH[1][11][b] + bn3));
                hn3 = nn + zz * (ho3 - nn); ho3 = hn3;
            }
            u32 lo = bfround(hn0) | (bfround(hn1) << 16);
            u32 hi = bfround(hn2) | (bfround(hn3) << 16);
            STA64(&hnxt[g * 32 + tid], (u64)lo | ((u64)hi << 32));
        }
        if (t < TT - 1 && tid < 64) {
            float s_ = boutv;
            #pragma unroll
            for (int cc = 0; cc < 12; ++cc) s_ += sOutPart[cc][o];
            out[((size_t)p3b * TT + (t + 1)) * PP + p3p] = s_;
        }
        rtarget += 8;
        grid_barrier32(leaf, root, rtarget, g);
        u64* tmp = hcur; hcur = hnxt; hnxt = tmp;
    }
    {
        u64 r0, r1, r2, r3, r4, r5, r6, r7, r8, r9, r10 = 0;
        #define LDH(J) LDA64(&hcur[tid + (J) * 768])
        r0 = LDH(0); r1 = LDH(1); r2 = LDH(2); r3 = LDH(3); r4 = LDH(4);
        r5 = LDH(5); r6 = LDH(6); r7 = LDH(7); r8 = LDH(8); r9 = LDH(9);
        if (tid < 512) r10 = LDH(10);
        #undef LDH
        sh[tid] = r0;          sh[tid + 768] = r1;   sh[tid + 1536] = r2;
        sh[tid + 2304] = r3;   sh[tid + 3072] = r4;  sh[tid + 3840] = r5;
        sh[tid + 4608] = r6;   sh[tid + 5376] = r7;  sh[tid + 6144] = r8;
        sh[tid + 6912] = r9;
        if (tid < 512) sh[tid + 7680] = r10;
        __syncthreads();
        p3partials();
        __syncthreads();
        if (tid < 64) {
            float s_ = boutv;
            #pragma unroll
            for (int cc = 0; cc < 12; ++cc) s_ += sOutPart[cc][o];
            out[((size_t)p3b * TT) * PP + p3p] = s_;
        }
    }
}

extern "C" void kernel_launch(void* const* d_in, const int* in_sizes, int n_in,
                              void* d_out, int out_size, void* d_ws, size_t ws_size,
                              hipStream_t stream) {
    const float* a      = (const float*)d_in[0];
    const float* h0     = (const float*)d_in[1];
    const float* Wih    = (const float*)d_in[2];
    const float* Whh    = (const float*)d_in[3];
    const float* bias   = (const float*)d_in[4];
    const float* bias_n = (const float*)d_in[5];
    const float* Wout   = (const float*)d_in[6];
    const float* bout   = (const float*)d_in[7];
    float* out = (float*)d_out;

    const size_t IG_BYTES = (size_t)TT * 64 * 3072;          // 805,306,368
    const size_t NEED     = IG_BYTES + 2 * 65536 + 4096;

    if (ws_size >= NEED) {
        char* igbase = (char*)d_ws;
        u64*  bufA  = (u64*)((char*)d_ws + IG_BYTES);
        u64*  bufB  = bufA + 8192;
        u32*  flags = (u32*)((char*)d_ws + IG_BYTES + 2 * 65536);
        hipMemsetAsync(flags, 0, 4096, stream);
        hipLaunchKernelGGL(ig_prepass16, dim3(16, 64), dim3(768), 0, stream,
                           a, Wih, bias, igbase);
        void* args[] = {(void*)&h0, (void*)&Whh, (void*)&bias_n, (void*)&Wout,
                        (void*)&bout, (void*)&igbase, (void*)&out,
                        (void*)&bufA, (void*)&bufB, (void*)&flags};
        hipLaunchCooperativeKernel((void*)gru_scan3, dim3(64), dim3(768),
                                   args, 0, stream);
    } else {
        u64* hA   = (u64*)d_ws;
        u64* hB   = hA + 8192;
        u32* leaf = (u32*)((char*)d_ws + 2 * 65536);
        u32* root = leaf + 8 * 16;
        hipMemsetAsync(leaf, 0, 1024, stream);
        void* args[] = {(void*)&a, (void*)&h0, (void*)&Wih, (void*)&Whh,
                        (void*)&bias, (void*)&bias_n, (void*)&Wout, (void*)&bout,
                        (void*)&out, (void*)&hA, (void*)&hB, (void*)&leaf, (void*)&root};
        hipLaunchCooperativeKernel((void*)gru_scan_fb, dim3(256), dim3(768),
                                   args, 0, stream);
    }
}

// Round 8
// 20304.396 us; speedup vs baseline: 1.5044x; 1.2089x over previous
//
#include <hip/hip_runtime.h>
#include <cstddef>

#define TT 4096
#define PP 512
#define WW 1024

using u32 = unsigned;
using u64 = unsigned long long;
using u16 = unsigned short;

typedef short short8 __attribute__((ext_vector_type(8)));
typedef float f32x4 __attribute__((ext_vector_type(4)));

__device__ __forceinline__ u32 bfround(float f) {
    u32 u = __float_as_uint(f);
    return (u + 0x7fffu + ((u >> 16) & 1u)) >> 16;
}
__device__ __forceinline__ float bf2f(u32 q) { return __uint_as_float(q << 16); }
__device__ __forceinline__ float bflo(u32 q) { return __uint_as_float(q << 16); }
__device__ __forceinline__ float bfhi(u32 q) { return __uint_as_float(q & 0xffff0000u); }

#define LDA64(p)    __hip_atomic_load((p),  __ATOMIC_RELAXED, __HIP_MEMORY_SCOPE_AGENT)
#define STA64(p, v) __hip_atomic_store((p), (v), __ATOMIC_RELAXED, __HIP_MEMORY_SCOPE_AGENT)
#define LDA32(p)    __hip_atomic_load((p),  __ATOMIC_RELAXED, __HIP_MEMORY_SCOPE_AGENT)
#define STA32(p, v) __hip_atomic_store((p), (v), __ATOMIC_RELAXED, __HIP_MEMORY_SCOPE_AGENT)
#define STA16(p, v) __hip_atomic_store((p), (v), __ATOMIC_RELAXED, __HIP_MEMORY_SCOPE_AGENT)

// ===================== a (f32) -> abf (bf16), same [b][t][p] layout =====================
__global__ __launch_bounds__(256) void a2bf(const float* __restrict__ a, u16* __restrict__ abf) {
    const size_t i = ((size_t)blockIdx.x * 256 + threadIdx.x) * 8;
    float4 lo = *(const float4*)&a[i];
    float4 hi = *(const float4*)&a[i + 4];
    uint4 w;
    w.x = bfround(lo.x) | (bfround(lo.y) << 16);
    w.y = bfround(lo.z) | (bfround(lo.w) << 16);
    w.z = bfround(hi.x) | (bfround(hi.y) << 16);
    w.w = bfround(hi.z) | (bfround(hi.w) << 16);
    *(uint4*)&abf[i] = w;
}

// ============ PREPASS v3: bf16 a, 8 gp-blocks, 2 row-tiles per wave ============
// ig layout: u16[((t*64 + gWG)*32 + b)*48 + slot], slot = gate*16 + (w&15)
__global__ __launch_bounds__(768, 1) void ig_prepass8(
    const u16* __restrict__ abf, const float* __restrict__ Wih,
    const float* __restrict__ bias, char* __restrict__ igbase)
{
    const int gp  = blockIdx.x;           // 0..7 (384 rows each)
    const int t0  = blockIdx.y * 64;
    const int tid = threadIdx.x;
    const int lane = tid & 63;
    const int wid  = tid >> 6;

    short8 af[2][16];
    float  bi[2][4];
    int    gWGv[2], slotv[2];
    #pragma unroll
    for (int rt2 = 0; rt2 < 2; ++rt2) {
        const int rowb = gp * 384 + rt2 * 192 + wid * 16;
        const float* wr = &Wih[(size_t)(rowb + (lane & 15)) * PP + (lane >> 4) * 8];
        #pragma unroll
        for (int s = 0; s < 16; ++s) {
            float t8[8];
            *(float4*)&t8[0] = *(const float4*)&wr[s * 32];
            *(float4*)&t8[4] = *(const float4*)&wr[s * 32 + 4];
            #pragma unroll
            for (int j = 0; j < 8; ++j) af[rt2][s][j] = (short)bfround(t8[j]);
        }
        const int grow0 = rowb + (lane >> 4) * 4;
        #pragma unroll
        for (int r = 0; r < 4; ++r) bi[rt2][r] = bias[grow0 + r];
        const int gate = grow0 >> 10, w = grow0 & 1023;
        gWGv[rt2] = w >> 4;
        slotv[rt2] = gate * 16 + (w & 15);
    }
    const int bcol = lane & 15;

    for (int ct = 0; ct < 128; ++ct) {
        const int t = t0 + (ct >> 1);
        const int b = (ct & 1) * 16 + bcol;
        const u16* ap = &abf[((size_t)b * TT + t) * PP + (lane >> 4) * 8];
        f32x4 d0 = {0.f, 0.f, 0.f, 0.f}, d1 = {0.f, 0.f, 0.f, 0.f};
        #pragma unroll 4
        for (int s = 0; s < 16; ++s) {
            short8 bf = *(const short8*)&ap[s * 32];
            d0 = __builtin_amdgcn_mfma_f32_16x16x32_bf16(af[0][s], bf, d0, 0, 0, 0);
            d1 = __builtin_amdgcn_mfma_f32_16x16x32_bf16(af[1][s], bf, d1, 0, 0, 0);
        }
        u32 l0 = bfround(d0[0] + bi[0][0]) | (bfround(d0[1] + bi[0][1]) << 16);
        u32 h0_ = bfround(d0[2] + bi[0][2]) | (bfround(d0[3] + bi[0][3]) << 16);
        u32 l1 = bfround(d1[0] + bi[1][0]) | (bfround(d1[1] + bi[1][1]) << 16);
        u32 h1_ = bfround(d1[2] + bi[1][2]) | (bfround(d1[3] + bi[1][3]) << 16);
        *(u64*)(igbase + (((size_t)t * 64 + gWGv[0]) * 1536 + (size_t)b * 48 + slotv[0]) * 2) = (u64)l0 | ((u64)h0_ << 32);
        *(u64*)(igbase + (((size_t)t * 64 + gWGv[1]) * 1536 + (size_t)b * 48 + slotv[1]) * 2) = (u64)l1 | ((u64)h1_ << 32);
    }
}

// ============ PREPASS v2 (mid-tier, f32 a, proven R7) ============
__global__ __launch_bounds__(768, 1) void ig_prepass16(
    const float* __restrict__ a, const float* __restrict__ Wih,
    const float* __restrict__ bias, char* __restrict__ igbase)
{
    const int gp   = blockIdx.x;
    const int t0   = blockIdx.y * 64;
    const int tid  = threadIdx.x;
    const int lane = tid & 63;
    const int wid  = tid >> 6;
    const int growb = gp * 192 + wid * 16;

    short8 afrag[16];
    float  biasv[4];
    {
        const float* wr = &Wih[(size_t)(growb + (lane & 15)) * PP + (lane >> 4) * 8];
        #pragma unroll
        for (int s = 0; s < 16; ++s) {
            float t8[8];
            *(float4*)&t8[0] = *(const float4*)&wr[s * 32];
            *(float4*)&t8[4] = *(const float4*)&wr[s * 32 + 4];
            #pragma unroll
            for (int j = 0; j < 8; ++j) afrag[s][j] = (short)bfround(t8[j]);
        }
        #pragma unroll
        for (int r = 0; r < 4; ++r) biasv[r] = bias[growb + (lane >> 4) * 4 + r];
    }
    const int grow0 = growb + (lane >> 4) * 4;
    const int gate  = grow0 >> 10;
    const int w     = grow0 & 1023;
    const int gWG   = w >> 4;
    const int slot  = gate * 16 + (w & 15);
    const int bcol  = lane & 15;

    for (int ct = 0; ct < 128; ++ct) {
        const int t = t0 + (ct >> 1);
        const int b = (ct & 1) * 16 + bcol;
        const float* ap = &a[((size_t)b * TT + t) * PP + (lane >> 4) * 8];
        f32x4 d = {0.f, 0.f, 0.f, 0.f};
        #pragma unroll 4
        for (int s = 0; s < 16; ++s) {
            float4 lo = *(const float4*)&ap[s * 32];
            float4 hi = *(const float4*)&ap[s * 32 + 4];
            short8 bfv;
            bfv[0] = (short)((__float_as_uint(lo.x) + 0x8000u) >> 16);
            bfv[1] = (short)((__float_as_uint(lo.y) + 0x8000u) >> 16);
            bfv[2] = (short)((__float_as_uint(lo.z) + 0x8000u) >> 16);
            bfv[3] = (short)((__float_as_uint(lo.w) + 0x8000u) >> 16);
            bfv[4] = (short)((__float_as_uint(hi.x) + 0x8000u) >> 16);
            bfv[5] = (short)((__float_as_uint(hi.y) + 0x8000u) >> 16);
            bfv[6] = (short)((__float_as_uint(hi.z) + 0x8000u) >> 16);
            bfv[7] = (short)((__float_as_uint(hi.w) + 0x8000u) >> 16);
            d = __builtin_amdgcn_mfma_f32_16x16x32_bf16(afrag[s], bfv, d, 0, 0, 0);
        }
        u32 lo32 = bfround(d[0] + biasv[0]) | (bfround(d[1] + biasv[1]) << 16);
        u32 hi32 = bfround(d[2] + biasv[2]) | (bfround(d[3] + biasv[3]) << 16);
        *(u64*)(igbase + (((size_t)t * 64 + gWG) * 1536 + (size_t)b * 48 + slot) * 2) =
            (u64)lo32 | ((u64)hi32 << 32);
    }
}

// ============ SCAN v4: direct B-frag loads, no LDS staging, slim barrier ============
// exchange layout: u64 idx decomposes so uint4 j = k8*32 + b = B-frag (8 k's, batch b);
// u64 pair (2j, 2j+1). hh waves 0-7 = (bt = wid>>2, kq = wid&3): 8 frags feed 3 gates.
// p3 waves 8-11: kq3 = wid-8, 8 frags each. Gates on tid>=256, out on tid<256.
__global__ __launch_bounds__(768, 1) void gru_scan4(
    const float* __restrict__ h0v, const float* __restrict__ Whh,
    const float* __restrict__ bias_n, const float* __restrict__ Wout,
    const float* __restrict__ bout, const char* __restrict__ igbase,
    float* __restrict__ out, u64* __restrict__ bufA, u64* __restrict__ bufB,
    u32* __restrict__ flags)
{
    __shared__ float sPreH[4][48][2][17];           // [kq][row][bhalf][16+1] : 2-way-free banks
    __shared__ float sOutP[4][16][18];
    __shared__ __align__(8) u64 sIgRaw[384];

    const int g    = blockIdx.x;                    // 0..63, owns w = g*16..+15
    const int tid  = threadIdx.x;
    const int lane = tid & 63;
    const int wid  = tid >> 6;
    const int p0   = (g >> 1) * 16;
    const int pb0  = (g & 1) * 16;

    // unified fragment array: hh waves use frag[0..23] (3 gates x 8 kslices),
    // p3 waves use frag[0..7] (Wout kslices)
    short8 frag[24];
    if (wid < 8) {
        const int kq = wid & 3;
        #pragma unroll
        for (int gate = 0; gate < 3; ++gate)
            #pragma unroll
            for (int s = 0; s < 8; ++s) {
                const float* wr = &Whh[(size_t)(gate * WW + g * 16 + (lane & 15)) * WW
                                       + (kq * 8 + s) * 32 + (lane >> 4) * 8];
                float t8[8];
                *(float4*)&t8[0] = *(const float4*)&wr[0];
                *(float4*)&t8[4] = *(const float4*)&wr[4];
                short8 v;
                #pragma unroll
                for (int j = 0; j < 8; ++j) v[j] = (short)bfround(t8[j]);
                frag[gate * 8 + s] = v;
            }
    } else {
        const int kq3 = wid - 8;
        #pragma unroll
        for (int s = 0; s < 8; ++s) {
            const float* wr = &Wout[(size_t)(p0 + (lane & 15)) * WW
                                    + (kq3 * 8 + s) * 32 + (lane >> 4) * 8];
            float t8[8];
            *(float4*)&t8[0] = *(const float4*)&wr[0];
            *(float4*)&t8[4] = *(const float4*)&wr[4];
            short8 v;
            #pragma unroll
            for (int j = 0; j < 8; ++j) v[j] = (short)bfround(t8[j]);
            frag[s] = v;
        }
    }

    // gate-thread state + h_init publish
    float h_own = 0.f, bnv = 0.f;
    int gwl = 0, gb = 0; u32 hidx16 = 0;
    if (tid >= 256) {
        const int idx = tid - 256;
        gwl = idx & 15; gb = idx >> 4;
        h_own = h0v[g * 16 + gwl];
        bnv   = bias_n[g * 16 + gwl];
        const int w_abs = g * 16 + gwl;
        const int ip = (w_abs >> 3) * 64 + 2 * gb + ((w_abs >> 2) & 1);
        hidx16 = 4 * ip + (w_abs & 3);
        STA16(&((u16*)bufA)[hidx16], (u16)bfround(h_own));
    }
    const float boutp = (tid < 256) ? bout[p0 + (tid & 15)] : 0.f;

    const int fo_hh = (lane >> 4) * 32 + ((wid >> 2) & 1) * 16 + (lane & 15);
    const int fo_p3 = (lane >> 4) * 32 + pb0 + (lane & 15);

    u64* hcur = bufA;
    u64* hnxt = bufB;
    u32 kk = 1;

    for (int t = TT - 1; t >= 0; --t) {
        // publisher-only drain, then one barrier, then flag
        if (wid >= 4) asm volatile("s_waitcnt vmcnt(0)" ::: "memory");
        __syncthreads();
        if (tid == 0) STA32(&flags[g * 16], kk);

        // issue ig load early (hides under the poll window)
        u64 igr = 0;
        if (tid < 384) igr = *(const u64*)(igbase + ((size_t)t * 64 + g) * 3072 + tid * 8);

        // every wave polls all 64 flags independently (no exit barrier)
        for (;;) {
            u32 v = LDA32(&flags[lane * 16]);
            if (__all((int)(v - kk) >= 0)) break;
            __builtin_amdgcn_s_sleep(1);
        }
        asm volatile("" ::: "memory");   // keep frag loads after the poll

        if (wid < 8) {
            const int kq = wid & 3;
            f32x4 c0 = {0.f,0.f,0.f,0.f}, c1 = {0.f,0.f,0.f,0.f}, c2 = {0.f,0.f,0.f,0.f};
            #pragma unroll
            for (int s = 0; s < 8; ++s) {
                const int ss = kq * 8 + s;
                const u64 q0 = LDA64(&hcur[2 * (ss * 128 + fo_hh)]);
                const u64 q1 = LDA64(&hcur[2 * (ss * 128 + fo_hh) + 1]);
                union { u64 q[2]; short8 v; } uu; uu.q[0] = q0; uu.q[1] = q1;
                c0 = __builtin_amdgcn_mfma_f32_16x16x32_bf16(frag[s],      uu.v, c0, 0, 0, 0);
                c1 = __builtin_amdgcn_mfma_f32_16x16x32_bf16(frag[8 + s],  uu.v, c1, 0, 0, 0);
                c2 = __builtin_amdgcn_mfma_f32_16x16x32_bf16(frag[16 + s], uu.v, c2, 0, 0, 0);
            }
            const int bt = wid >> 2, r0 = (lane >> 4) * 4, col = lane & 15;
            #pragma unroll
            for (int r = 0; r < 4; ++r) {
                sPreH[kq][r0 + r][bt][col]      = c0[r];
                sPreH[kq][16 + r0 + r][bt][col] = c1[r];
                sPreH[kq][32 + r0 + r][bt][col] = c2[r];
            }
        } else {
            const int kq3 = wid - 8;
            f32x4 d = {0.f, 0.f, 0.f, 0.f};
            #pragma unroll
            for (int s = 0; s < 8; ++s) {
                const int ss = kq3 * 8 + s;
                const u64 q0 = LDA64(&hcur[2 * (ss * 128 + fo_p3)]);
                const u64 q1 = LDA64(&hcur[2 * (ss * 128 + fo_p3) + 1]);
                union { u64 q[2]; short8 v; } uu; uu.q[0] = q0; uu.q[1] = q1;
                d = __builtin_amdgcn_mfma_f32_16x16x32_bf16(frag[s], uu.v, d, 0, 0, 0);
            }
            const int r0 = (lane >> 4) * 4, col = lane & 15;
            #pragma unroll
            for (int r = 0; r < 4; ++r) sOutP[kq3][r0 + r][col] = d[r];
        }
        if (tid < 384) sIgRaw[tid] = igr;
        __syncthreads();

        // gate phase (tid>=256) / out store (tid<256, reads sOutP race-free here)
        if (tid >= 256) {
            const u16* sIgU = (const u16*)sIgRaw;
            const float ig_r = bf2f(sIgU[gb * 48 + gwl]);
            const float ig_z = bf2f(sIgU[gb * 48 + 16 + gwl]);
            const float ig_n = bf2f(sIgU[gb * 48 + 32 + gwl]);
            const int bh = gb >> 4, bc = gb & 15;
            const float hg_r = sPreH[0][gwl][bh][bc] + sPreH[1][gwl][bh][bc]
                             + sPreH[2][gwl][bh][bc] + sPreH[3][gwl][bh][bc];
            const float hg_z = sPreH[0][16 + gwl][bh][bc] + sPreH[1][16 + gwl][bh][bc]
                             + sPreH[2][16 + gwl][bh][bc] + sPreH[3][16 + gwl][bh][bc];
            const float hg_n = sPreH[0][32 + gwl][bh][bc] + sPreH[1][32 + gwl][bh][bc]
                             + sPreH[2][32 + gwl][bh][bc] + sPreH[3][32 + gwl][bh][bc];
            const float rr = __builtin_amdgcn_rcpf(1.f + __expf(-(ig_r + hg_r)));
            const float zz = __builtin_amdgcn_rcpf(1.f + __expf(-(ig_z + hg_z)));
            const float xn = ig_n + rr * (hg_n + bnv);
            const float nn = 2.f * __builtin_amdgcn_rcpf(1.f + __expf(-2.f * xn)) - 1.f;
            h_own = nn + zz * (h_own - nn);
            STA16(&((u16*)hnxt)[hidx16], (u16)bfround(h_own));
        } else if (t < TT - 1) {
            const int p = tid & 15, b = tid >> 4;
            const float s_ = boutp + sOutP[0][p][b] + sOutP[1][p][b]
                                   + sOutP[2][p][b] + sOutP[3][p][b];
            out[((size_t)(pb0 + b) * TT + (t + 1)) * PP + p0 + p] = s_;
        }

        u64* tmp = hcur; hcur = hnxt; hnxt = tmp;
        ++kk;
    }

    // ---- epilogue: project hs[0] -> out[:,0,:] ----
    if (wid >= 4) asm volatile("s_waitcnt vmcnt(0)" ::: "memory");
    __syncthreads();
    if (tid == 0) STA32(&flags[g * 16], kk);
    if (wid >= 8) {
        for (;;) {
            u32 v = LDA32(&flags[lane * 16]);
            if (__all((int)(v - kk) >= 0)) break;
            __builtin_amdgcn_s_sleep(1);
        }
        asm volatile("" ::: "memory");
        const int kq3 = wid - 8;
        f32x4 d = {0.f, 0.f, 0.f, 0.f};
        #pragma unroll
        for (int s = 0; s < 8; ++s) {
            const int ss = kq3 * 8 + s;
            const u64 q0 = LDA64(&hcur[2 * (ss * 128 + fo_p3)]);
            const u64 q1 = LDA64(&hcur[2 * (ss * 128 + fo_p3) + 1]);
            union { u64 q[2]; short8 v; } uu; uu.q[0] = q0; uu.q[1] = q1;
            d = __builtin_amdgcn_mfma_f32_16x16x32_bf16(frag[s], uu.v, d, 0, 0, 0);
        }
        const int r0 = (lane >> 4) * 4, col = lane & 15;
        #pragma unroll
        for (int r = 0; r < 4; ++r) sOutP[kq3][r0 + r][col] = d[r];
    }
    __syncthreads();
    if (tid < 256) {
        const int p = tid & 15, b = tid >> 4;
        const float s_ = boutp + sOutP[0][p][b] + sOutP[1][p][b]
                               + sOutP[2][p][b] + sOutP[3][p][b];
        out[((size_t)(pb0 + b) * TT) * PP + p0 + p] = s_;
    }
}

// ===================== FALLBACK (proven R3 kernel, 256 WGs) =====================
__device__ __forceinline__ void grid_barrier32(u32* leaf, u32* root, u32 rtarget, int g) {
    asm volatile("s_waitcnt vmcnt(0)" ::: "memory");
    __syncthreads();
    if (threadIdx.x == 0) {
        u32 old = __hip_atomic_fetch_add(&leaf[(g & 7) * 16], 1u,
                                         __ATOMIC_RELAXED, __HIP_MEMORY_SCOPE_AGENT);
        if ((old & 31u) == 31u)
            __hip_atomic_fetch_add(root, 1u, __ATOMIC_RELAXED, __HIP_MEMORY_SCOPE_AGENT);
        while (__hip_atomic_load(root, __ATOMIC_RELAXED, __HIP_MEMORY_SCOPE_AGENT) < rtarget)
            __builtin_amdgcn_s_sleep(2);
    }
    __syncthreads();
}

__global__ __launch_bounds__(768, 1) void gru_scan_fb(
    const float* __restrict__ a, const float* __restrict__ h0,
    const float* __restrict__ Wih, const float* __restrict__ Whh,
    const float* __restrict__ bias, const float* __restrict__ bias_n,
    const float* __restrict__ Wout, const float* __restrict__ bout,
    float* __restrict__ out, u64* __restrict__ hbufA, u64* __restrict__ hbufB,
    u32* __restrict__ leaf, u32* __restrict__ root)
{
    __shared__ float sWhh[12][WW];
    __shared__ __align__(16) u64 sh[8192];
    __shared__ float sPreH[2][12][32];
    __shared__ float sIg[2][2][12][32];
    __shared__ float sOutPart[12][64];

    const int g   = blockIdx.x;
    const int tid = threadIdx.x;
    const int w0  = g * 4;

    for (int i = tid; i < 12 * (WW / 4); i += 768) {
        int row_ = i / (WW / 4);
        int k4_  = i - row_ * (WW / 4);
        int gr   = (row_ >> 2) * WW + w0 + (row_ & 3);
        *(float4*)&sWhh[row_][k4_ * 4] = *(const float4*)&Whh[(size_t)gr * WW + k4_ * 4];
    }
    const int  half = (tid >= 384) ? 1 : 0;
    const int  sub  = tid - half * 384;
    const int  b1   = sub & 31;
    const int  row  = sub >> 5;
    const int  grow = (row >> 2) * WW + w0 + (row & 3);
    const float biasv = (half == 0) ? bias[grow] : 0.0f;

    float ho0 = 0.f, ho1 = 0.f, ho2 = 0.f, ho3 = 0.f;
    float bn0 = 0.f, bn1 = 0.f, bn2 = 0.f, bn3 = 0.f;
    if (tid < 32) {
        ho0 = h0[w0 + 0]; ho1 = h0[w0 + 1]; ho2 = h0[w0 + 2]; ho3 = h0[w0 + 3];
        bn0 = bias_n[w0 + 0]; bn1 = bias_n[w0 + 1]; bn2 = bias_n[w0 + 2]; bn3 = bias_n[w0 + 3];
        u32 lo = bfround(ho0) | (bfround(ho1) << 16);
        u32 hi = bfround(ho2) | (bfround(ho3) << 16);
        STA64(&hbufA[g * 32 + tid], (u64)lo | ((u64)hi << 32));
    }
    const int  p0  = (g & 31) * 16;
    const int  b0  = (g >> 5) * 4;
    const int  o   = tid & 63;
    const int  c   = tid >> 6;
    const int  p3p = p0 + (o & 15);
    const int  p3b = b0 + (o >> 4);
    const float boutv = bout[p3p];

    auto ihdot = [&](int t_, int pbuf) {
        const float4* __restrict__ arow = (const float4*)&a[((size_t)b1 * TT + t_) * PP];
        const float4* __restrict__ wrow = (const float4*)&Wih[(size_t)grow * PP];
        const int p40 = half * 64;
        float4 acc = {0.f, 0.f, 0.f, 0.f};
        #pragma unroll 8
        for (int p4 = 0; p4 < 64; ++p4) {
            float4 av = arow[p40 + p4];
            float4 wv = wrow[p40 + p4];
            acc.x += av.x * wv.x; acc.y += av.y * wv.y;
            acc.z += av.z * wv.z; acc.w += av.w * wv.w;
        }
        sIg[pbuf][half][row][b1] = (acc.x + acc.y) + (acc.z + acc.w) + biasv;
    };
    auto p3partials = [&]() {
        const float4* __restrict__ wrow = (const float4*)&Wout[(size_t)p3p * WW];
        float4 acc = {0.f, 0.f, 0.f, 0.f};
        for (int k4 = c; k4 < WW / 4; k4 += 12) {
            u64 pk = sh[k4 * 32 + p3b];
            float4 wv = wrow[k4];
            acc.x += bflo((u32)pk) * wv.x;
            acc.y += bfhi((u32)pk) * wv.y;
            acc.z += bflo((u32)(pk >> 32)) * wv.z;
            acc.w += bfhi((u32)(pk >> 32)) * wv.w;
        }
        sOutPart[c][o] = (acc.x + acc.y) + (acc.z + acc.w);
    };

    ihdot(TT - 1, 1);
    u32 rtarget = 8;
    grid_barrier32(leaf, root, rtarget, g);
    u64* hcur = hbufA;
    u64* hnxt = hbufB;

    for (int t = TT - 1; t >= 0; --t) {
        const int par = t & 1;
        u64 r0, r1, r2, r3, r4, r5, r6, r7, r8, r9, r10 = 0;
        #define LDH(J) LDA64(&hcur[tid + (J) * 768])
        r0 = LDH(0); r1 = LDH(1); r2 = LDH(2); r3 = LDH(3); r4 = LDH(4);
        r5 = LDH(5); r6 = LDH(6); r7 = LDH(7); r8 = LDH(8); r9 = LDH(9);
        if (tid < 512) r10 = LDH(10);
        #undef LDH
        if (t > 0) ihdot(t - 1, par ^ 1);
        sh[tid] = r0;          sh[tid + 768] = r1;   sh[tid + 1536] = r2;
        sh[tid + 2304] = r3;   sh[tid + 3072] = r4;  sh[tid + 3840] = r5;
        sh[tid + 4608] = r6;   sh[tid + 5376] = r7;  sh[tid + 6144] = r8;
        sh[tid + 6912] = r9;
        if (tid < 512) sh[tid + 7680] = r10;
        __syncthreads();
        {
            const int k40 = half * 128;
            float4 acc = {0.f, 0.f, 0.f, 0.f};
            #pragma unroll 4
            for (int k4 = 0; k4 < 128; ++k4) {
                u64 pk = sh[(k40 + k4) * 32 + b1];
                float4 wv = *(const float4*)&sWhh[row][(k40 + k4) * 4];
                acc.x += bflo((u32)pk) * wv.x;
                acc.y += bfhi((u32)pk) * wv.y;
                acc.z += bflo((u32)(pk >> 32)) * wv.z;
                acc.w += bfhi((u32)(pk >> 32)) * wv.w;
            }
            sPreH[half][row][b1] = (acc.x + acc.y) + (acc.z + acc.w);
        }
        if (t < TT - 1) p3partials();
        __syncthreads();
        if (tid < 32) {
            const int b = tid;
            float hn0, hn1, hn2, hn3;
            {
                float rr = 1.f / (1.f + __expf(-(sIg[par][0][0][b] + sIg[par][1][0][b] + sPreH[0][0][b] + sPreH[1][0][b])));
                float zz = 1.f / (1.f + __expf(-(sIg[par][0][4][b] + sIg[par][1][4][b] + sPreH[0][4][b] + sPreH[1][4][b])));
                float nn = tanhf(sIg[par][0][8][b] + sIg[par][1][8][b] + rr * (sPreH[0][8][b] + sPreH[1][8][b] + bn0));
                hn0 = nn + zz * (ho0 - nn); ho0 = hn0;
            }
            {
                float rr = 1.f / (1.f + __expf(-(sIg[par][0][1][b] + sIg[par][1][1][b] + sPreH[0][1][b] + sPreH[1][1][b])));
                float zz = 1.f / (1.f + __expf(-(sIg[par][0][5][b] + sIg[par][1][5][b] + sPreH[0][5][b] + sPreH[1][5][b])));
                float nn = tanhf(sIg[par][0][9][b] + sIg[par][1][9][b] + rr * (sPreH[0][9][b] + sPreH[1][9][b] + bn1));
                hn1 = nn + zz * (ho1 - nn); ho1 = hn1;
            }
            {
                float rr = 1.f / (1.f + __expf(-(sIg[par][0][2][b] + sIg[par][1][2][b] + sPreH[0][2][b] + sPreH[1][2][b])));
                float zz = 1.f / (1.f + __expf(-(sIg[par][0][6][b] + sIg[par][1][6][b] + sPreH[0][6][b] + sPreH[1][6][b])));
                float nn = tanhf(sIg[par][0][10][b] + sIg[par][1][10][b] + rr * (sPreH[0][10][b] + sPreH[1][10][b] + bn2));
                hn2 = nn + zz * (ho2 - nn); ho2 = hn2;
            }
            {
                float rr = 1.f / (1.f + __expf(-(sIg[par][0][3][b] + sIg[par][1][3][b] + sPreH[0][3][b] + sPreH[1][3][b])));
                float zz = 1.f / (1.f + __expf(-(sIg[par][0][7][b] + sIg[par][1][7][b] + sPreH[0][7][b] + sPreH[1][7][b])));
                float nn = tanhf(sIg[par][0][11][b] + sIg[par][1][11][b] + rr * (sPreH[0][11][b] + sPreH[1][11][b] + bn3));
                hn3 = nn + zz * (ho3 - nn); ho3 = hn3;
            }
            u32 lo = bfround(hn0) | (bfround(hn1) << 16);
            u32 hi = bfround(hn2) | (bfround(hn3) << 16);
            STA64(&hnxt[g * 32 + tid], (u64)lo | ((u64)hi << 32));
        }
        if (t < TT - 1 && tid < 64) {
            float s_ = boutv;
            #pragma unroll
            for (int cc = 0; cc < 12; ++cc) s_ += sOutPart[cc][o];
            out[((size_t)p3b * TT + (t + 1)) * PP + p3p] = s_;
        }
        rtarget += 8;
        grid_barrier32(leaf, root, rtarget, g);
        u64* tmp = hcur; hcur = hnxt; hnxt = tmp;
    }
    {
        u64 r0, r1, r2, r3, r4, r5, r6, r7, r8, r9, r10 = 0;
        #define LDH(J) LDA64(&hcur[tid + (J) * 768])
        r0 = LDH(0); r1 = LDH(1); r2 = LDH(2); r3 = LDH(3); r4 = LDH(4);
        r5 = LDH(5); r6 = LDH(6); r7 = LDH(7); r8 = LDH(8); r9 = LDH(9);
        if (tid < 512) r10 = LDH(10);
        #undef LDH
        sh[tid] = r0;          sh[tid + 768] = r1;   sh[tid + 1536] = r2;
        sh[tid + 2304] = r3;   sh[tid + 3072] = r4;  sh[tid + 3840] = r5;
        sh[tid + 4608] = r6;   sh[tid + 5376] = r7;  sh[tid + 6144] = r8;
        sh[tid + 6912] = r9;
        if (tid < 512) sh[tid + 7680] = r10;
        __syncthreads();
        p3partials();
        __syncthreads();
        if (tid < 64) {
            float s_ = boutv;
            #pragma unroll
            for (int cc = 0; cc < 12; ++cc) s_ += sOutPart[cc][o];
            out[((size_t)p3b * TT) * PP + p3p] = s_;
        }
    }
}

extern "C" void kernel_launch(void* const* d_in, const int* in_sizes, int n_in,
                              void* d_out, int out_size, void* d_ws, size_t ws_size,
                              hipStream_t stream) {
    const float* a      = (const float*)d_in[0];
    const float* h0     = (const float*)d_in[1];
    const float* Wih    = (const float*)d_in[2];
    const float* Whh    = (const float*)d_in[3];
    const float* bias   = (const float*)d_in[4];
    const float* bias_n = (const float*)d_in[5];
    const float* Wout   = (const float*)d_in[6];
    const float* bout   = (const float*)d_in[7];
    float* out = (float*)d_out;

    const size_t IG_BYTES  = (size_t)TT * 64 * 3072;      // 805,306,368
    const size_t ABF_BYTES = (size_t)32 * TT * PP * 2;    // 134,217,728
    const size_t NEED_FULL = IG_BYTES + ABF_BYTES + 2 * 65536 + 4096;
    const size_t NEED_MID  = IG_BYTES + 2 * 65536 + 4096;

    if (ws_size >= NEED_FULL) {
        char* igbase = (char*)d_ws;
        u16*  abf    = (u16*)((char*)d_ws + IG_BYTES);
        u64*  bufA   = (u64*)((char*)d_ws + IG_BYTES + ABF_BYTES);
        u64*  bufB   = bufA + 8192;
        u32*  flags  = (u32*)((char*)d_ws + IG_BYTES + ABF_BYTES + 2 * 65536);
        hipMemsetAsync(flags, 0, 4096, stream);
        hipLaunchKernelGGL(a2bf, dim3(32768), dim3(256), 0, stream, a, abf);
        hipLaunchKernelGGL(ig_prepass8, dim3(8, 64), dim3(768), 0, stream,
                           abf, Wih, bias, igbase);
        void* args[] = {(void*)&h0, (void*)&Whh, (void*)&bias_n, (void*)&Wout,
                        (void*)&bout, (void*)&igbase, (void*)&out,
                        (void*)&bufA, (void*)&bufB, (void*)&flags};
        hipLaunchCooperativeKernel((void*)gru_scan4, dim3(64), dim3(768),
                                   args, 0, stream);
    } else if (ws_size >= NEED_MID) {
        char* igbase = (char*)d_ws;
        u64*  bufA   = (u64*)((char*)d_ws + IG_BYTES);
        u64*  bufB   = bufA + 8192;
        u32*  flags  = (u32*)((char*)d_ws + IG_BYTES + 2 * 65536);
        hipMemsetAsync(flags, 0, 4096, stream);
        hipLaunchKernelGGL(ig_prepass16, dim3(16, 64), dim3(768), 0, stream,
                           a, Wih, bias, igbase);
        void* args[] = {(void*)&h0, (void*)&Whh, (void*)&bias_n, (void*)&Wout,
                        (void*)&bout, (void*)&igbase, (void*)&out,
                        (void*)&bufA, (void*)&bufB, (void*)&flags};
        hipLaunchCooperativeKernel((void*)gru_scan4, dim3(64), dim3(768),
                                   args, 0, stream);
    } else {
        u64* hA   = (u64*)d_ws;
        u64* hB   = hA + 8192;
        u32* leaf = (u32*)((char*)d_ws + 2 * 65536);
        u32* root = leaf + 8 * 16;
        hipMemsetAsync(leaf, 0, 1024, stream);
        void* args[] = {(void*)&a, (void*)&h0, (void*)&Wih, (void*)&Whh,
                        (void*)&bias, (void*)&bias_n, (void*)&Wout, (void*)&bout,
                        (void*)&out, (void*)&hA, (void*)&hB, (void*)&leaf, (void*)&root};
        hipLaunchCooperativeKernel((void*)gru_scan_fb, dim3(256), dim3(768),
                                   args, 0, stream);
    }
}